// Round 2
// baseline (1523.782 us; speedup 1.0000x reference)
//
#include <hip/hip_runtime.h>
#include <math.h>

// Problem constants
#define B      2048
#define N      100000
#define DD     64
#define HH     256
#define KK     20
#define SAMPLE 4096
#define CAP    1536
#define RB     64      // rows per block in gemm kernels

#define INF_F (__builtin_inff())

__device__ __forceinline__ float wsum64(float v) {
    #pragma unroll
    for (int o = 32; o > 0; o >>= 1) v += __shfl_xor(v, o, 64);
    return v;
}

// 16 FMAs: acc += dot(x[0..15], d0..d3)
#define FMA16(a, xr)                                                         \
    do {                                                                     \
        a = fmaf(xr[0],  d0.x, a); a = fmaf(xr[1],  d0.y, a);                \
        a = fmaf(xr[2],  d0.z, a); a = fmaf(xr[3],  d0.w, a);                \
        a = fmaf(xr[4],  d1.x, a); a = fmaf(xr[5],  d1.y, a);                \
        a = fmaf(xr[6],  d1.z, a); a = fmaf(xr[7],  d1.w, a);                \
        a = fmaf(xr[8],  d2.x, a); a = fmaf(xr[9],  d2.y, a);                \
        a = fmaf(xr[10], d2.z, a); a = fmaf(xr[11], d2.w, a);                \
        a = fmaf(xr[12], d3.x, a); a = fmaf(xr[13], d3.y, a);                \
        a = fmaf(xr[14], d3.z, a); a = fmaf(xr[15], d3.w, a);                \
    } while (0)

// ---------------------------------------------------------------- prep ------
__global__ __launch_bounds__(64) void prep_kernel(const float* __restrict__ z,
                                                  float* __restrict__ xs,
                                                  float* __restrict__ xnorm) {
    int b = blockIdx.x, d = threadIdx.x;
    float v = z[b * 66 + d];
    xs[b * 64 + d] = v;
    float s = wsum64(v * v);
    if (d == 0) xnorm[b] = s;
}

// --------------------------------------------------------------- dnorm ------
// 16 lanes per candidate: coalesced float4 reads, shfl reduce within group
__global__ __launch_bounds__(256) void dnorm_kernel(const float* __restrict__ data,
                                                    float* __restrict__ dnorm) {
    int gt = blockIdx.x * 256 + threadIdx.x;
    int j = gt >> 4;          // candidate
    int l = gt & 15;          // lane within group
    if (j >= N) return;
    const float4* dp = reinterpret_cast<const float4*>(data + (size_t)j * 64);
    float4 v = dp[l];
    float s = v.x * v.x + v.y * v.y + v.z * v.z + v.w * v.w;
    #pragma unroll
    for (int o = 1; o < 16; o <<= 1) s += __shfl_xor(s, o, 64);
    if (l == 0) dnorm[j] = s;
}

// ---------------------------------------------------------------- mlp -------
__global__ __launch_bounds__(256) void mlp_kernel(const float* __restrict__ z,
                                                  const float* __restrict__ tp,
                                                  const float* __restrict__ W1,
                                                  const float* __restrict__ b1,
                                                  const float* __restrict__ W2,
                                                  const float* __restrict__ b2,
                                                  float* __restrict__ xdot) {
    __shared__ float sin_[8][65];
    __shared__ float shid[8][HH];
    int tid = threadIdx.x;
    int row0 = blockIdx.x * 8;
    float tval = tp[0];
    for (int idx = tid; idx < 8 * 64; idx += 256) {
        int r = idx >> 6, d = idx & 63;
        sin_[r][d] = z[(row0 + r) * 66 + d];
    }
    if (tid < 8) sin_[tid][64] = tval;
    __syncthreads();

    int h = tid;
    float acc[8];
    #pragma unroll
    for (int r = 0; r < 8; ++r) acc[r] = b1[h];
    for (int i = 0; i < 65; ++i) {
        float wv = W1[i * HH + h];
        #pragma unroll
        for (int r = 0; r < 8; ++r) acc[r] = fmaf(sin_[r][i], wv, acc[r]);
    }
    #pragma unroll
    for (int r = 0; r < 8; ++r) shid[r][h] = fmaxf(acc[r], 0.f);
    __syncthreads();

    int d = tid & 63, rb = tid >> 6;
    for (int rr = rb; rr < 8; rr += 4) {
        float a = b2[d];
        #pragma unroll 8
        for (int hh2 = 0; hh2 < HH; ++hh2)
            a = fmaf(shid[rr][hh2], W2[hh2 * 64 + d], a);
        xdot[(size_t)(row0 + rr) * 64 + d] = a;
    }
}

// ----------------------------------------------------------- sample gemm ----
// exact sq distances to candidates [0, 4096), written densely
__global__ __launch_bounds__(256, 4) void sample_gemm(const float* __restrict__ data,
                                                      const float* __restrict__ xs,
                                                      const float* __restrict__ xnorm,
                                                      const float* __restrict__ dnorm,
                                                      float* __restrict__ samp) {
    int tid = threadIdx.x;
    int row0 = blockIdx.x * RB;
    int j = blockIdx.y * 1024 + 0;
    for (int c = 0; c < 4; ++c) {
        int jj = blockIdx.y * 1024 + c * 256 + tid;
        const float4* dp = reinterpret_cast<const float4*>(data + (size_t)jj * 64);
        float dn = dnorm[jj];
        #pragma unroll 1
        for (int rt = 0; rt < 4; ++rt) {
            float acc[16];
            #pragma unroll
            for (int r = 0; r < 16; ++r) acc[r] = 0.f;
            #pragma unroll
            for (int kb = 0; kb < 4; ++kb) {
                float4 d0 = dp[kb * 4 + 0], d1 = dp[kb * 4 + 1];
                float4 d2 = dp[kb * 4 + 2], d3 = dp[kb * 4 + 3];
                #pragma unroll
                for (int r = 0; r < 16; ++r) {
                    const float* xr = xs + ((row0 + rt * 16 + r) * 64 + kb * 16);
                    float a = acc[r];
                    FMA16(a, xr);
                    acc[r] = a;
                }
            }
            #pragma unroll
            for (int r = 0; r < 16; ++r) {
                int row = row0 + rt * 16 + r;
                float sq = xnorm[row] + dn - 2.0f * acc[r];
                samp[(size_t)row * SAMPLE + jj] = sq;
            }
        }
    }
    (void)j;
}

// ------------------------------------------------------------ thr select ----
// thr[row] = 20th smallest of the 4096 sampled sq values (>= true 20th of N)
__global__ __launch_bounds__(256) void thr_select(const float* __restrict__ samp,
                                                  float* __restrict__ thr) {
    __shared__ float s[SAMPLE];
    __shared__ float wmin[4];
    __shared__ int   wpos[4];
    int row = blockIdx.x, tid = threadIdx.x;
    for (int i = tid; i < SAMPLE; i += 256) s[i] = samp[(size_t)row * SAMPLE + i];
    __syncthreads();
    for (int k = 0; k < KK; ++k) {
        float v = INF_F; int p = -1;
        #pragma unroll
        for (int u = 0; u < SAMPLE / 256; ++u) {
            int i = u * 256 + tid;
            float x = s[i];
            if (x < v) { v = x; p = i; }
        }
        #pragma unroll
        for (int o = 32; o > 0; o >>= 1) {
            float ov = __shfl_xor(v, o, 64);
            int op = __shfl_xor(p, o, 64);
            if (ov < v) { v = ov; p = op; }
        }
        if ((tid & 63) == 0) { wmin[tid >> 6] = v; wpos[tid >> 6] = p; }
        __syncthreads();
        if (tid == 0) {
            float bv = wmin[0]; int bp = wpos[0];
            #pragma unroll
            for (int w = 1; w < 4; ++w)
                if (wmin[w] < bv) { bv = wmin[w]; bp = wpos[w]; }
            if (bp >= 0) s[bp] = INF_F;
            if (k == KK - 1) thr[row] = bv;
        }
        __syncthreads();
    }
}

// -------------------------------------------------------------- knn gemm ----
// full scan: push (sq, j) with sq <= thr[row] into per-row buffers
__global__ __launch_bounds__(256, 4) void knn_gemm(const float* __restrict__ data,
                                                   const float* __restrict__ xs,
                                                   const float* __restrict__ xnorm,
                                                   const float* __restrict__ dnorm,
                                                   const float* __restrict__ thr,
                                                   int* __restrict__ cnt,
                                                   float* __restrict__ bufd,
                                                   int* __restrict__ bufi) {
    int tid = threadIdx.x;
    int row0 = blockIdx.x * RB;
    for (int c = 0; c < 4; ++c) {
        int j = blockIdx.y * 1024 + c * 256 + tid;
        bool valid = (j < N);
        int jc = valid ? j : (N - 1);
        const float4* dp = reinterpret_cast<const float4*>(data + (size_t)jc * 64);
        float dn = dnorm[jc];
        #pragma unroll 1
        for (int rt = 0; rt < 4; ++rt) {
            float acc[16];
            #pragma unroll
            for (int r = 0; r < 16; ++r) acc[r] = 0.f;
            #pragma unroll
            for (int kb = 0; kb < 4; ++kb) {
                float4 d0 = dp[kb * 4 + 0], d1 = dp[kb * 4 + 1];
                float4 d2 = dp[kb * 4 + 2], d3 = dp[kb * 4 + 3];
                #pragma unroll
                for (int r = 0; r < 16; ++r) {
                    const float* xr = xs + ((row0 + rt * 16 + r) * 64 + kb * 16);
                    float a = acc[r];
                    FMA16(a, xr);
                    acc[r] = a;
                }
            }
            #pragma unroll
            for (int r = 0; r < 16; ++r) {
                int row = row0 + rt * 16 + r;
                float sq = xnorm[row] + dn - 2.0f * acc[r];
                if (valid && sq <= thr[row]) {
                    int pos = atomicAdd(&cnt[row], 1);
                    if (pos < CAP) {
                        bufd[(size_t)row * CAP + pos] = sq;
                        bufi[(size_t)row * CAP + pos] = j;
                    }
                }
            }
        }
    }
}

// --------------------------------------------------------- select + finish --
__global__ __launch_bounds__(64) void select_finish(const float* __restrict__ bufd,
                                                    const int* __restrict__ bufi,
                                                    const int* __restrict__ cnt,
                                                    const float* __restrict__ xdot,
                                                    const float* __restrict__ vel,
                                                    float* __restrict__ out) {
    __shared__ float sd[CAP];
    __shared__ int   si[CAP];
    __shared__ float seld[KK];
    __shared__ int   seli[KK];
    __shared__ float selw[KK];
    int row = blockIdx.x, lane = threadIdx.x;
    int n = cnt[row];
    if (n > CAP) n = CAP;
    for (int i = lane; i < n; i += 64) {
        sd[i] = bufd[(size_t)row * CAP + i];
        si[i] = bufi[(size_t)row * CAP + i];
    }
    __syncthreads();
    for (int k = 0; k < KK; ++k) {
        float v = INF_F; int id = 0x7fffffff; int p = -1;
        for (int i = lane; i < n; i += 64) {
            float x = sd[i]; int xi = si[i];
            if (x < v || (x == v && xi < id)) { v = x; id = xi; p = i; }
        }
        #pragma unroll
        for (int o = 32; o > 0; o >>= 1) {
            float ov = __shfl_xor(v, o, 64);
            int oid = __shfl_xor(id, o, 64);
            int op  = __shfl_xor(p, o, 64);
            if (ov < v || (ov == v && oid < id)) { v = ov; id = oid; p = op; }
        }
        if (lane == 0) {
            seld[k] = v; seli[k] = id;
            if (p >= 0) sd[p] = INF_F;
        }
        __syncthreads();
    }
    float d20 = sqrtf(fmaxf(seld[KK - 1], 1e-30f));
    float h = fmaxf(d20, 1e-12f);
    float wk = 0.f;
    if (lane < KK) {
        float dd = sqrtf(fmaxf(seld[lane], 1e-30f));
        wk = expf(-(dd * dd) / (2.f * h * h));
    }
    float tot = wsum64(wk) + 1e-12f;
    if (lane < KK) selw[lane] = wk / tot;
    __syncthreads();
    float u = 0.f;
    #pragma unroll
    for (int k = 0; k < KK; ++k)
        u = fmaf(selw[k], vel[(size_t)seli[k] * 64 + lane], u);
    float xd = xdot[(size_t)row * 64 + lane];
    float du  = wsum64(u * xd);
    float nu2 = wsum64(u * u);
    float nx2 = wsum64(xd * xd);
    float l2  = wsum64((u - xd) * (u - xd));
    float nu = fmaxf(sqrtf(nu2), 1e-8f);
    float nx = fmaxf(sqrtf(nx2), 1e-8f);
    out[(size_t)row * 66 + lane] = xd;
    if (lane == 0) {
        out[(size_t)row * 66 + 64] = 1.f - du / (nu * nx);
        out[(size_t)row * 66 + 65] = l2;
    }
}

// ---------------------------------------------------------------------------
extern "C" void kernel_launch(void* const* d_in, const int* in_sizes, int n_in,
                              void* d_out, int out_size, void* d_ws, size_t ws_size,
                              hipStream_t stream) {
    const float* t_   = (const float*)d_in[0];
    const float* z    = (const float*)d_in[1];
    const float* data = (const float*)d_in[2];
    const float* vel  = (const float*)d_in[3];
    const float* W1   = (const float*)d_in[4];
    const float* b1   = (const float*)d_in[5];
    const float* W2   = (const float*)d_in[6];
    const float* b2   = (const float*)d_in[7];
    float* out = (float*)d_out;

    // workspace layout (floats)
    float* xs    = (float*)d_ws;                 // 2048*64
    float* xnorm = xs + B * DD;                  // 2048
    float* xdot  = xnorm + B;                    // 2048*64
    float* thr   = xdot + B * DD;                // 2048
    int*   cnt   = (int*)(thr + B);              // 2048
    float* dnorm = (float*)(cnt + B);            // 100000
    float* samp  = dnorm + N;                    // 2048*4096
    float* bufd  = samp + (size_t)B * SAMPLE;    // 2048*1536
    int*   bufi  = (int*)(bufd + (size_t)B * CAP);

    hipMemsetAsync(cnt, 0, B * sizeof(int), stream);
    prep_kernel<<<B, 64, 0, stream>>>(z, xs, xnorm);
    dnorm_kernel<<<(N * 16 + 255) / 256, 256, 0, stream>>>(data, dnorm);
    mlp_kernel<<<B / 8, 256, 0, stream>>>(z, t_, W1, b1, W2, b2, xdot);
    sample_gemm<<<dim3(B / RB, 4), 256, 0, stream>>>(data, xs, xnorm, dnorm, samp);
    thr_select<<<B, 256, 0, stream>>>(samp, thr);
    knn_gemm<<<dim3(B / RB, 98), 256, 0, stream>>>(data, xs, xnorm, dnorm, thr, cnt, bufd, bufi);
    select_finish<<<B, 64, 0, stream>>>(bufd, bufi, cnt, xdot, vel, out);
}

// Round 3
// 743.507 us; speedup vs baseline: 2.0495x; 2.0495x over previous
//
#include <hip/hip_runtime.h>
#include <math.h>

// Problem constants
#define B      2048
#define N      100000
#define DD     64
#define HH     256
#define KK     20
#define SAMPLE 4096
#define CAP    1536

// GEMM tile
#define TM 64
#define TN 128
#define TKK 64

#define INF_F (__builtin_inff())

__device__ __forceinline__ float wsum64(float v) {
    #pragma unroll
    for (int o = 32; o > 0; o >>= 1) v += __shfl_xor(v, o, 64);
    return v;
}

// ---------------------------------------------------------------- prep ------
__global__ __launch_bounds__(64) void prep_kernel(const float* __restrict__ z,
                                                  float* __restrict__ xs,
                                                  float* __restrict__ xnorm) {
    int b = blockIdx.x, d = threadIdx.x;
    float v = z[b * 66 + d];
    xs[b * 64 + d] = v;
    float s = wsum64(v * v);
    if (d == 0) xnorm[b] = s;
}

// --------------------------------------------------------------- dnorm ------
__global__ __launch_bounds__(256) void dnorm_kernel(const float* __restrict__ data,
                                                    float* __restrict__ dnorm) {
    int gt = blockIdx.x * 256 + threadIdx.x;
    int j = gt >> 4;
    int l = gt & 15;
    if (j >= N) return;
    const float4* dp = reinterpret_cast<const float4*>(data + (size_t)j * 64);
    float4 v = dp[l];
    float s = v.x * v.x + v.y * v.y + v.z * v.z + v.w * v.w;
    #pragma unroll
    for (int o = 1; o < 16; o <<= 1) s += __shfl_xor(s, o, 64);
    if (l == 0) dnorm[j] = s;
}

// ---------------------------------------------------------------- mlp -------
__global__ __launch_bounds__(256) void mlp_kernel(const float* __restrict__ z,
                                                  const float* __restrict__ tp,
                                                  const float* __restrict__ W1,
                                                  const float* __restrict__ b1,
                                                  const float* __restrict__ W2,
                                                  const float* __restrict__ b2,
                                                  float* __restrict__ xdot) {
    __shared__ float sin_[8][65];
    __shared__ float shid[8][HH];
    int tid = threadIdx.x;
    int row0 = blockIdx.x * 8;
    float tval = tp[0];
    for (int idx = tid; idx < 8 * 64; idx += 256) {
        int r = idx >> 6, d = idx & 63;
        sin_[r][d] = z[(row0 + r) * 66 + d];
    }
    if (tid < 8) sin_[tid][64] = tval;
    __syncthreads();

    int h = tid;
    float acc[8];
    #pragma unroll
    for (int r = 0; r < 8; ++r) acc[r] = b1[h];
    for (int i = 0; i < 65; ++i) {
        float wv = W1[i * HH + h];
        #pragma unroll
        for (int r = 0; r < 8; ++r) acc[r] = fmaf(sin_[r][i], wv, acc[r]);
    }
    #pragma unroll
    for (int r = 0; r < 8; ++r) shid[r][h] = fmaxf(acc[r], 0.f);
    __syncthreads();

    int d = tid & 63, rb = tid >> 6;
    for (int rr = rb; rr < 8; rr += 4) {
        float a = b2[d];
        #pragma unroll 8
        for (int hh2 = 0; hh2 < HH; ++hh2)
            a = fmaf(shid[rr][hh2], W2[hh2 * 64 + d], a);
        xdot[(size_t)(row0 + rr) * 64 + d] = a;
    }
}

// ------------------------------------------------------- tiled dist GEMM ----
// M=64 rows x N=128 candidates x K=64, per-thread 4x8 register tile.
// DENSE=true: write sq densely into samp (sample pass, j0 < 4096).
// DENSE=false: push (sq, j) with sq <= thr[row] into per-row buffers.
template <bool DENSE>
__global__ __launch_bounds__(256) void dist_kernel(const float* __restrict__ data,
                                                   const float* __restrict__ xs,
                                                   const float* __restrict__ xnorm,
                                                   const float* __restrict__ dnorm,
                                                   const float* __restrict__ thr,
                                                   int* __restrict__ cnt,
                                                   float* __restrict__ bufd,
                                                   int* __restrict__ bufi,
                                                   float* __restrict__ samp) {
    __shared__ float sx[TKK][TM];   // 16 KB, [k][m]
    __shared__ float sd[TKK][TN];   // 32 KB, [k][n]
    int tid = threadIdx.x;
    int row0 = blockIdx.x * TM;
    int j0 = blockIdx.y * TN;

    // stage x tile (transpose [m][k] -> [k][m]); writes conflict-free (m consecutive)
    #pragma unroll
    for (int p = 0; p < 4; ++p) {
        int flat = p * 256 + tid;
        int m = flat & 63, k4 = flat >> 6;
        float4 v = *reinterpret_cast<const float4*>(xs + (row0 + m) * 64 + k4 * 4);
        sx[k4 * 4 + 0][m] = v.x;
        sx[k4 * 4 + 1][m] = v.y;
        sx[k4 * 4 + 2][m] = v.z;
        sx[k4 * 4 + 3][m] = v.w;
    }
    // stage d tile (transpose [n][k] -> [k][n]); writes conflict-free (n consecutive)
    #pragma unroll
    for (int p = 0; p < 8; ++p) {
        int flat = p * 256 + tid;
        int n = flat & 127, k4 = flat >> 7;
        int jc = j0 + n;
        if (jc > N - 1) jc = N - 1;
        float4 v = *reinterpret_cast<const float4*>(data + (size_t)jc * 64 + k4 * 4);
        sd[k4 * 4 + 0][n] = v.x;
        sd[k4 * 4 + 1][n] = v.y;
        sd[k4 * 4 + 2][n] = v.z;
        sd[k4 * 4 + 3][n] = v.w;
    }
    __syncthreads();

    int tx = tid & 15, ty = tid >> 4;
    int m0 = ty * 4, n0 = tx * 8;
    float acc[4][8];
    #pragma unroll
    for (int r = 0; r < 4; ++r)
        #pragma unroll
        for (int c = 0; c < 8; ++c) acc[r][c] = 0.f;

    #pragma unroll 8
    for (int k = 0; k < TKK; ++k) {
        float4 a  = *reinterpret_cast<const float4*>(&sx[k][m0]);
        float4 b0 = *reinterpret_cast<const float4*>(&sd[k][n0]);
        float4 b1 = *reinterpret_cast<const float4*>(&sd[k][n0 + 4]);
        float av[4] = {a.x, a.y, a.z, a.w};
        float bv[8] = {b0.x, b0.y, b0.z, b0.w, b1.x, b1.y, b1.z, b1.w};
        #pragma unroll
        for (int r = 0; r < 4; ++r)
            #pragma unroll
            for (int c = 0; c < 8; ++c)
                acc[r][c] = fmaf(av[r], bv[c], acc[r][c]);
    }

    // epilogue
    float xn[4], th[4];
    #pragma unroll
    for (int r = 0; r < 4; ++r) {
        xn[r] = xnorm[row0 + m0 + r];
        th[r] = DENSE ? 0.f : thr[row0 + m0 + r];
    }
    float dn_[8];
    #pragma unroll
    for (int c = 0; c < 8; ++c) {
        int j = j0 + n0 + c;
        dn_[c] = dnorm[j < N ? j : N - 1];
    }
    #pragma unroll
    for (int r = 0; r < 4; ++r) {
        int row = row0 + m0 + r;
        #pragma unroll
        for (int c = 0; c < 8; ++c) {
            int j = j0 + n0 + c;
            float sq = xn[r] + dn_[c] - 2.0f * acc[r][c];
            if (DENSE) {
                samp[(size_t)row * SAMPLE + j] = sq;
            } else if (j < N && sq <= th[r]) {
                int pos = atomicAdd(&cnt[row], 1);
                if (pos < CAP) {
                    bufd[(size_t)row * CAP + pos] = sq;
                    bufi[(size_t)row * CAP + pos] = j;
                }
            }
        }
    }
}

// ------------------------------------------------------------ thr select ----
__global__ __launch_bounds__(256) void thr_select(const float* __restrict__ samp,
                                                  float* __restrict__ thr) {
    __shared__ float s[SAMPLE];
    __shared__ float wmin[4];
    __shared__ int   wpos[4];
    int row = blockIdx.x, tid = threadIdx.x;
    for (int i = tid; i < SAMPLE; i += 256) s[i] = samp[(size_t)row * SAMPLE + i];
    __syncthreads();
    for (int k = 0; k < KK; ++k) {
        float v = INF_F; int p = -1;
        #pragma unroll
        for (int u = 0; u < SAMPLE / 256; ++u) {
            int i = u * 256 + tid;
            float x = s[i];
            if (x < v) { v = x; p = i; }
        }
        #pragma unroll
        for (int o = 32; o > 0; o >>= 1) {
            float ov = __shfl_xor(v, o, 64);
            int op = __shfl_xor(p, o, 64);
            if (ov < v) { v = ov; p = op; }
        }
        if ((tid & 63) == 0) { wmin[tid >> 6] = v; wpos[tid >> 6] = p; }
        __syncthreads();
        if (tid == 0) {
            float bv = wmin[0]; int bp = wpos[0];
            #pragma unroll
            for (int w = 1; w < 4; ++w)
                if (wmin[w] < bv) { bv = wmin[w]; bp = wpos[w]; }
            if (bp >= 0) s[bp] = INF_F;
            if (k == KK - 1) thr[row] = bv;
        }
        __syncthreads();
    }
}

// --------------------------------------------------------- select + finish --
__global__ __launch_bounds__(64) void select_finish(const float* __restrict__ bufd,
                                                    const int* __restrict__ bufi,
                                                    const int* __restrict__ cnt,
                                                    const float* __restrict__ xdot,
                                                    const float* __restrict__ vel,
                                                    float* __restrict__ out) {
    __shared__ float sd[CAP];
    __shared__ int   si[CAP];
    __shared__ float seld[KK];
    __shared__ int   seli[KK];
    __shared__ float selw[KK];
    int row = blockIdx.x, lane = threadIdx.x;
    int n = cnt[row];
    if (n > CAP) n = CAP;
    for (int i = lane; i < n; i += 64) {
        sd[i] = bufd[(size_t)row * CAP + i];
        si[i] = bufi[(size_t)row * CAP + i];
    }
    __syncthreads();
    for (int k = 0; k < KK; ++k) {
        float v = INF_F; int id = 0x7fffffff; int p = -1;
        for (int i = lane; i < n; i += 64) {
            float x = sd[i]; int xi = si[i];
            if (x < v || (x == v && xi < id)) { v = x; id = xi; p = i; }
        }
        #pragma unroll
        for (int o = 32; o > 0; o >>= 1) {
            float ov = __shfl_xor(v, o, 64);
            int oid = __shfl_xor(id, o, 64);
            int op  = __shfl_xor(p, o, 64);
            if (ov < v || (ov == v && oid < id)) { v = ov; id = oid; p = op; }
        }
        if (lane == 0) {
            seld[k] = v; seli[k] = id;
            if (p >= 0) sd[p] = INF_F;
        }
        __syncthreads();
    }
    float d20 = sqrtf(fmaxf(seld[KK - 1], 1e-30f));
    float h = fmaxf(d20, 1e-12f);
    float wk = 0.f;
    if (lane < KK) {
        float dd = sqrtf(fmaxf(seld[lane], 1e-30f));
        wk = expf(-(dd * dd) / (2.f * h * h));
    }
    float tot = wsum64(wk) + 1e-12f;
    if (lane < KK) selw[lane] = wk / tot;
    __syncthreads();
    float u = 0.f;
    #pragma unroll
    for (int k = 0; k < KK; ++k)
        u = fmaf(selw[k], vel[(size_t)seli[k] * 64 + lane], u);
    float xd = xdot[(size_t)row * 64 + lane];
    float du  = wsum64(u * xd);
    float nu2 = wsum64(u * u);
    float nx2 = wsum64(xd * xd);
    float l2  = wsum64((u - xd) * (u - xd));
    float nu = fmaxf(sqrtf(nu2), 1e-8f);
    float nx = fmaxf(sqrtf(nx2), 1e-8f);
    out[(size_t)row * 66 + lane] = xd;
    if (lane == 0) {
        out[(size_t)row * 66 + 64] = 1.f - du / (nu * nx);
        out[(size_t)row * 66 + 65] = l2;
    }
}

// ---------------------------------------------------------------------------
extern "C" void kernel_launch(void* const* d_in, const int* in_sizes, int n_in,
                              void* d_out, int out_size, void* d_ws, size_t ws_size,
                              hipStream_t stream) {
    const float* t_   = (const float*)d_in[0];
    const float* z    = (const float*)d_in[1];
    const float* data = (const float*)d_in[2];
    const float* vel  = (const float*)d_in[3];
    const float* W1   = (const float*)d_in[4];
    const float* b1   = (const float*)d_in[5];
    const float* W2   = (const float*)d_in[6];
    const float* b2   = (const float*)d_in[7];
    float* out = (float*)d_out;

    // workspace layout (floats)
    float* xs    = (float*)d_ws;                 // 2048*64
    float* xnorm = xs + B * DD;                  // 2048
    float* xdot  = xnorm + B;                    // 2048*64
    float* thr   = xdot + B * DD;                // 2048
    int*   cnt   = (int*)(thr + B);              // 2048
    float* dnorm = (float*)(cnt + B);            // 100000
    float* samp  = dnorm + N;                    // 2048*4096
    float* bufd  = samp + (size_t)B * SAMPLE;    // 2048*1536
    int*   bufi  = (int*)(bufd + (size_t)B * CAP);

    hipMemsetAsync(cnt, 0, B * sizeof(int), stream);
    prep_kernel<<<B, 64, 0, stream>>>(z, xs, xnorm);
    dnorm_kernel<<<(N * 16 + 255) / 256, 256, 0, stream>>>(data, dnorm);
    mlp_kernel<<<B / 8, 256, 0, stream>>>(z, t_, W1, b1, W2, b2, xdot);
    dist_kernel<true><<<dim3(B / TM, SAMPLE / TN), 256, 0, stream>>>(
        data, xs, xnorm, dnorm, nullptr, nullptr, nullptr, nullptr, samp);
    thr_select<<<B, 256, 0, stream>>>(samp, thr);
    dist_kernel<false><<<dim3(B / TM, (N + TN - 1) / TN), 256, 0, stream>>>(
        data, xs, xnorm, dnorm, thr, cnt, bufd, bufi, nullptr);
    select_finish<<<B, 64, 0, stream>>>(bufd, bufi, cnt, xdot, vel, out);
}

// Round 4
// 635.391 us; speedup vs baseline: 2.3982x; 1.1702x over previous
//
#include <hip/hip_runtime.h>
#include <math.h>

// Problem constants
#define B      2048
#define N      100000
#define NPAD   100096   // 782 * 128
#define DD     64
#define HH     256
#define KK     20
#define SAMPLE 4096
#define CAP    1536
#define SSEL   320
#define SLACK  1.5f

#define INF_F (__builtin_inff())

typedef __bf16 bf16x8 __attribute__((ext_vector_type(8)));
typedef float  floatx4 __attribute__((ext_vector_type(4)));
union U16 { uint4 u; bf16x8 v; };

__device__ __forceinline__ float wsum64(float v) {
    #pragma unroll
    for (int o = 32; o > 0; o >>= 1) v += __shfl_xor(v, o, 64);
    return v;
}

// ---------------------------------------------------------------- prep ------
__global__ __launch_bounds__(64) void prep_kernel(const float* __restrict__ z,
                                                  float* __restrict__ xs,
                                                  float* __restrict__ xnorm,
                                                  __bf16* __restrict__ xs_h) {
    int b = blockIdx.x, d = threadIdx.x;
    float v = z[b * 66 + d];
    xs[b * 64 + d] = v;
    xs_h[b * 64 + d] = (__bf16)v;
    float s = wsum64(v * v);
    if (d == 0) xnorm[b] = s;
}

// --------------------------------------------------------------- dnorm ------
__global__ __launch_bounds__(256) void dnorm_kernel(const float* __restrict__ data,
                                                    float* __restrict__ dnorm) {
    int gt = blockIdx.x * 256 + threadIdx.x;
    int j = gt >> 4;
    int l = gt & 15;
    if (j >= N) return;
    const float4* dp = reinterpret_cast<const float4*>(data + (size_t)j * 64);
    float4 v = dp[l];
    float s = v.x * v.x + v.y * v.y + v.z * v.z + v.w * v.w;
    #pragma unroll
    for (int o = 1; o < 16; o <<= 1) s += __shfl_xor(s, o, 64);
    if (l == 0) dnorm[j] = s;
}

// ---------------------------------------------------------- convert data ----
__global__ __launch_bounds__(256) void convert_data(const float* __restrict__ data,
                                                    __bf16* __restrict__ d_hi) {
    int idx = blockIdx.x * 256 + threadIdx.x;
    if (idx >= NPAD * 64) return;
    int j = idx >> 6;
    float v = (j < N) ? data[idx] : 0.f;
    d_hi[idx] = (__bf16)v;
}

// ---------------------------------------------------------------- mlp -------
__global__ __launch_bounds__(256) void mlp_kernel(const float* __restrict__ z,
                                                  const float* __restrict__ tp,
                                                  const float* __restrict__ W1,
                                                  const float* __restrict__ b1,
                                                  const float* __restrict__ W2,
                                                  const float* __restrict__ b2,
                                                  float* __restrict__ xdot) {
    __shared__ float sin_[8][65];
    __shared__ float shid[8][HH];
    int tid = threadIdx.x;
    int row0 = blockIdx.x * 8;
    float tval = tp[0];
    for (int idx = tid; idx < 8 * 64; idx += 256) {
        int r = idx >> 6, d = idx & 63;
        sin_[r][d] = z[(row0 + r) * 66 + d];
    }
    if (tid < 8) sin_[tid][64] = tval;
    __syncthreads();

    int h = tid;
    float acc[8];
    #pragma unroll
    for (int r = 0; r < 8; ++r) acc[r] = b1[h];
    for (int i = 0; i < 65; ++i) {
        float wv = W1[i * HH + h];
        #pragma unroll
        for (int r = 0; r < 8; ++r) acc[r] = fmaf(sin_[r][i], wv, acc[r]);
    }
    #pragma unroll
    for (int r = 0; r < 8; ++r) shid[r][h] = fmaxf(acc[r], 0.f);
    __syncthreads();

    int d = tid & 63, rb = tid >> 6;
    for (int rr = rb; rr < 8; rr += 4) {
        float a = b2[d];
        #pragma unroll 8
        for (int hh2 = 0; hh2 < HH; ++hh2)
            a = fmaf(shid[rr][hh2], W2[hh2 * 64 + d], a);
        xdot[(size_t)(row0 + rr) * 64 + d] = a;
    }
}

// ------------------------------------------------ exact sample dist GEMM ----
// M=64 x N=128 x K=64 fp32 tile; writes sq densely into samp (4096 cols)
__global__ __launch_bounds__(256) void sample_gemm(const float* __restrict__ data,
                                                   const float* __restrict__ xs,
                                                   const float* __restrict__ xnorm,
                                                   const float* __restrict__ dnorm,
                                                   float* __restrict__ samp) {
    __shared__ float sx[64][64];
    __shared__ float sd[64][128];
    int tid = threadIdx.x;
    int row0 = blockIdx.x * 64;
    int j0 = blockIdx.y * 128;
    #pragma unroll
    for (int p = 0; p < 4; ++p) {
        int flat = p * 256 + tid;
        int m = flat & 63, k4 = flat >> 6;
        float4 v = *reinterpret_cast<const float4*>(xs + (row0 + m) * 64 + k4 * 4);
        sx[k4 * 4 + 0][m] = v.x; sx[k4 * 4 + 1][m] = v.y;
        sx[k4 * 4 + 2][m] = v.z; sx[k4 * 4 + 3][m] = v.w;
    }
    #pragma unroll
    for (int p = 0; p < 8; ++p) {
        int flat = p * 256 + tid;
        int n = flat & 127, k4 = flat >> 7;
        float4 v = *reinterpret_cast<const float4*>(data + (size_t)(j0 + n) * 64 + k4 * 4);
        sd[k4 * 4 + 0][n] = v.x; sd[k4 * 4 + 1][n] = v.y;
        sd[k4 * 4 + 2][n] = v.z; sd[k4 * 4 + 3][n] = v.w;
    }
    __syncthreads();

    int tx = tid & 15, ty = tid >> 4;
    int m0 = ty * 4, n0 = tx * 8;
    float acc[4][8];
    #pragma unroll
    for (int r = 0; r < 4; ++r)
        #pragma unroll
        for (int c = 0; c < 8; ++c) acc[r][c] = 0.f;
    #pragma unroll 8
    for (int k = 0; k < 64; ++k) {
        float4 a  = *reinterpret_cast<const float4*>(&sx[k][m0]);
        float4 b0 = *reinterpret_cast<const float4*>(&sd[k][n0]);
        float4 b1 = *reinterpret_cast<const float4*>(&sd[k][n0 + 4]);
        float av[4] = {a.x, a.y, a.z, a.w};
        float bv[8] = {b0.x, b0.y, b0.z, b0.w, b1.x, b1.y, b1.z, b1.w};
        #pragma unroll
        for (int r = 0; r < 4; ++r)
            #pragma unroll
            for (int c = 0; c < 8; ++c)
                acc[r][c] = fmaf(av[r], bv[c], acc[r][c]);
    }
    #pragma unroll
    for (int r = 0; r < 4; ++r) {
        int row = row0 + m0 + r;
        float xn = xnorm[row];
        #pragma unroll
        for (int c = 0; c < 8; ++c) {
            int j = j0 + n0 + c;
            samp[(size_t)row * SAMPLE + j] = xn + dnorm[j] - 2.0f * acc[r][c];
        }
    }
}

// ------------------------------------------------------------ thr select ----
__global__ __launch_bounds__(256) void thr_select(const float* __restrict__ samp,
                                                  float* __restrict__ thr) {
    __shared__ float s[SAMPLE];
    __shared__ float wmin[4];
    __shared__ int   wpos[4];
    int row = blockIdx.x, tid = threadIdx.x;
    for (int i = tid; i < SAMPLE; i += 256) s[i] = samp[(size_t)row * SAMPLE + i];
    __syncthreads();
    for (int k = 0; k < KK; ++k) {
        float v = INF_F; int p = -1;
        #pragma unroll
        for (int u = 0; u < SAMPLE / 256; ++u) {
            int i = u * 256 + tid;
            float x = s[i];
            if (x < v) { v = x; p = i; }
        }
        #pragma unroll
        for (int o = 32; o > 0; o >>= 1) {
            float ov = __shfl_xor(v, o, 64);
            int op = __shfl_xor(p, o, 64);
            if (ov < v) { v = ov; p = op; }
        }
        if ((tid & 63) == 0) { wmin[tid >> 6] = v; wpos[tid >> 6] = p; }
        __syncthreads();
        if (tid == 0) {
            float bv = wmin[0]; int bp = wpos[0];
            #pragma unroll
            for (int w = 1; w < 4; ++w)
                if (wmin[w] < bv) { bv = wmin[w]; bp = wpos[w]; }
            if (bp >= 0) s[bp] = INF_F;
            if (k == KK - 1) thr[row] = bv;
        }
        __syncthreads();
    }
}

// ------------------------------------------------------ bf16 MFMA filter ----
// 128x128 tile, K=64 (2 mfma k-steps), appends (sq_b, j) with sq_b <= thr+SLACK
__global__ __launch_bounds__(256) void gemm_filter(const __bf16* __restrict__ xs_h,
                                                   const __bf16* __restrict__ d_hi,
                                                   const float* __restrict__ xnorm,
                                                   const float* __restrict__ dnorm,
                                                   const float* __restrict__ thr,
                                                   int* __restrict__ cnt,
                                                   float* __restrict__ bufd,
                                                   int* __restrict__ bufi) {
    __shared__ uint4 sA[8][128];   // chunk-major: [k-chunk][m] of 8 bf16
    __shared__ uint4 sB[8][128];   // [k-chunk][n]
    __shared__ float sXN[128], sTH[128], sDN[128];
    int tid = threadIdx.x;
    int m0 = blockIdx.x * 128;
    int j0 = blockIdx.y * 128;

    #pragma unroll
    for (int p = 0; p < 4; ++p) {
        int flat = p * 256 + tid;
        int m = flat & 127, c = flat >> 7;
        sA[c][m] = reinterpret_cast<const uint4*>(xs_h + (size_t)(m0 + m) * 64)[c];
    }
    #pragma unroll
    for (int p = 0; p < 4; ++p) {
        int flat = p * 256 + tid;
        int n = flat & 127, c = flat >> 7;
        sB[c][n] = reinterpret_cast<const uint4*>(d_hi + (size_t)(j0 + n) * 64)[c];
    }
    if (tid < 128) {
        sXN[tid] = xnorm[m0 + tid];
        sTH[tid] = thr[m0 + tid];
    } else {
        int n = tid - 128;
        int j = j0 + n;
        sDN[n] = (j < N) ? dnorm[j] : 0.f;
    }
    __syncthreads();

    int wv = tid >> 6;
    int wm = wv & 1, wn = wv >> 1;
    int lane = tid & 63;
    int l16 = lane & 15, quad = lane >> 4;

    floatx4 acc[4][4];
    #pragma unroll
    for (int mt = 0; mt < 4; ++mt)
        #pragma unroll
        for (int nt = 0; nt < 4; ++nt)
            acc[mt][nt] = (floatx4){0.f, 0.f, 0.f, 0.f};

    #pragma unroll
    for (int s = 0; s < 2; ++s) {
        bf16x8 af[4], bfr[4];
        #pragma unroll
        for (int mt = 0; mt < 4; ++mt) {
            U16 u; u.u = sA[s * 4 + quad][wm * 64 + mt * 16 + l16]; af[mt] = u.v;
        }
        #pragma unroll
        for (int nt = 0; nt < 4; ++nt) {
            U16 u; u.u = sB[s * 4 + quad][wn * 64 + nt * 16 + l16]; bfr[nt] = u.v;
        }
        #pragma unroll
        for (int mt = 0; mt < 4; ++mt)
            #pragma unroll
            for (int nt = 0; nt < 4; ++nt)
                acc[mt][nt] = __builtin_amdgcn_mfma_f32_16x16x32_bf16(
                    af[mt], bfr[nt], acc[mt][nt], 0, 0, 0);
    }

    #pragma unroll
    for (int mt = 0; mt < 4; ++mt) {
        #pragma unroll
        for (int nt = 0; nt < 4; ++nt) {
            floatx4 a4 = acc[mt][nt];
            int nloc = wn * 64 + nt * 16 + l16;
            int j = j0 + nloc;
            float dn = sDN[nloc];
            #pragma unroll
            for (int rg = 0; rg < 4; ++rg) {
                int mloc = wm * 64 + mt * 16 + quad * 4 + rg;
                float sqb = sXN[mloc] + dn - 2.0f * a4[rg];
                if (j < N && sqb <= sTH[mloc] + SLACK) {
                    int row = m0 + mloc;
                    int pos = atomicAdd(&cnt[row], 1);
                    if (pos < CAP) {
                        bufd[(size_t)row * CAP + pos] = sqb;
                        bufi[(size_t)row * CAP + pos] = j;
                    }
                }
            }
        }
    }
}

// --------------------------------------------------------- select + finish --
// approx-20th -> exact fp32 recompute of near-boundary set -> exact top-20
__global__ __launch_bounds__(64) void select_finish(const float* __restrict__ bufd,
                                                    const int* __restrict__ bufi,
                                                    const int* __restrict__ cnt,
                                                    const float* __restrict__ xs,
                                                    const float* __restrict__ xnorm,
                                                    const float* __restrict__ dnorm,
                                                    const float* __restrict__ data,
                                                    const float* __restrict__ xdot,
                                                    const float* __restrict__ vel,
                                                    float* __restrict__ out) {
    __shared__ float sd[CAP];
    __shared__ int   si[CAP];
    __shared__ float sx[64];
    __shared__ float se[SSEL];
    __shared__ int   sj[SSEL];
    __shared__ int   scnt;
    __shared__ float seld[KK];
    __shared__ int   seli[KK];
    __shared__ float selw[KK];
    int row = blockIdx.x, lane = threadIdx.x;
    int n = cnt[row];
    if (n > CAP) n = CAP;
    for (int i = lane; i < n; i += 64) {
        sd[i] = bufd[(size_t)row * CAP + i];
        si[i] = bufi[(size_t)row * CAP + i];
    }
    sx[lane] = xs[row * 64 + lane];
    if (lane == 0) scnt = 0;
    __syncthreads();

    // T = 20th smallest approx; extracted candidates appended to S as we go
    float T = INF_F;
    for (int k = 0; k < KK; ++k) {
        float v = INF_F; int p = -1;
        for (int i = lane; i < n; i += 64) {
            float x = sd[i];
            if (x < v) { v = x; p = i; }
        }
        #pragma unroll
        for (int o = 32; o > 0; o >>= 1) {
            float ov = __shfl_xor(v, o, 64);
            int op = __shfl_xor(p, o, 64);
            if (ov < v) { v = ov; p = op; }
        }
        T = v;
        if (lane == 0 && p >= 0) {
            sd[p] = INF_F;
            int q = scnt++;
            sj[q] = si[p];
        }
        __syncthreads();
    }
    // rest of S: approx within 2*SLACK of T
    for (int i = lane; i < n; i += 64) {
        if (sd[i] <= T + 2.0f * SLACK) {
            int q = atomicAdd(&scnt, 1);
            if (q < SSEL) sj[q] = si[i];
        }
    }
    __syncthreads();
    int m = scnt < SSEL ? scnt : SSEL;
    // exact fp32 recompute (bit-identical chain: sequential fmaf k ascending)
    for (int c = lane; c < m; c += 64) {
        int j = sj[c];
        const float4* dp = reinterpret_cast<const float4*>(data + (size_t)j * 64);
        float dot = 0.f;
        #pragma unroll
        for (int kb = 0; kb < 16; ++kb) {
            float4 q = dp[kb];
            dot = fmaf(sx[kb * 4 + 0], q.x, dot);
            dot = fmaf(sx[kb * 4 + 1], q.y, dot);
            dot = fmaf(sx[kb * 4 + 2], q.z, dot);
            dot = fmaf(sx[kb * 4 + 3], q.w, dot);
        }
        se[c] = xnorm[row] + dnorm[j] - 2.0f * dot;
    }
    __syncthreads();
    // exact top-20 over S, tie-break smaller j (matches lax.top_k)
    for (int k = 0; k < KK; ++k) {
        float v = INF_F; int id = 0x7fffffff; int p = -1;
        for (int i = lane; i < m; i += 64) {
            float x = se[i]; int xi = sj[i];
            if (x < v || (x == v && xi < id)) { v = x; id = xi; p = i; }
        }
        #pragma unroll
        for (int o = 32; o > 0; o >>= 1) {
            float ov = __shfl_xor(v, o, 64);
            int oid = __shfl_xor(id, o, 64);
            int op  = __shfl_xor(p, o, 64);
            if (ov < v || (ov == v && oid < id)) { v = ov; id = oid; p = op; }
        }
        if (lane == 0) {
            seld[k] = v; seli[k] = id;
            if (p >= 0) se[p] = INF_F;
        }
        __syncthreads();
    }
    float d20 = sqrtf(fmaxf(seld[KK - 1], 1e-30f));
    float h = fmaxf(d20, 1e-12f);
    float wk = 0.f;
    if (lane < KK) {
        float dd = sqrtf(fmaxf(seld[lane], 1e-30f));
        wk = expf(-(dd * dd) / (2.f * h * h));
    }
    float tot = wsum64(wk) + 1e-12f;
    if (lane < KK) selw[lane] = wk / tot;
    __syncthreads();
    float u = 0.f;
    #pragma unroll
    for (int k = 0; k < KK; ++k)
        u = fmaf(selw[k], vel[(size_t)seli[k] * 64 + lane], u);
    float xd = xdot[(size_t)row * 64 + lane];
    float du  = wsum64(u * xd);
    float nu2 = wsum64(u * u);
    float nx2 = wsum64(xd * xd);
    float l2  = wsum64((u - xd) * (u - xd));
    float nu = fmaxf(sqrtf(nu2), 1e-8f);
    float nx = fmaxf(sqrtf(nx2), 1e-8f);
    out[(size_t)row * 66 + lane] = xd;
    if (lane == 0) {
        out[(size_t)row * 66 + 64] = 1.f - du / (nu * nx);
        out[(size_t)row * 66 + 65] = l2;
    }
}

// ---------------------------------------------------------------------------
extern "C" void kernel_launch(void* const* d_in, const int* in_sizes, int n_in,
                              void* d_out, int out_size, void* d_ws, size_t ws_size,
                              hipStream_t stream) {
    const float* t_   = (const float*)d_in[0];
    const float* z    = (const float*)d_in[1];
    const float* data = (const float*)d_in[2];
    const float* vel  = (const float*)d_in[3];
    const float* W1   = (const float*)d_in[4];
    const float* b1   = (const float*)d_in[5];
    const float* W2   = (const float*)d_in[6];
    const float* b2   = (const float*)d_in[7];
    float* out = (float*)d_out;

    // workspace layout (float slots, all 16B-aligned)
    float*  xs    = (float*)d_ws;                    // 131072
    float*  xnorm = xs + 131072;                     // 2048
    float*  xdot  = xnorm + 2048;                    // 131072
    float*  thr   = xdot + 131072;                   // 2048
    int*    cnt   = (int*)(thr + 2048);              // 2048
    float*  dnorm = (float*)(cnt + 2048);            // 100096 (padded)
    __bf16* xs_h  = (__bf16*)(dnorm + 100096);       // 131072 bf16 = 65536 f
    float*  R     = (float*)(xs_h + 131072);         // overlap region
    // phase 1: samp (2048*4096 f) lives at R
    // phase 2: d_hi (NPAD*64 bf16 = 3203072 f), bufd, bufi
    float*  samp  = R;
    __bf16* d_hi  = (__bf16*)R;
    float*  bufd  = R + 3203072;                     // 2048*1536
    int*    bufi  = (int*)(bufd + (size_t)B * CAP);  // 2048*1536

    hipMemsetAsync(cnt, 0, B * sizeof(int), stream);
    prep_kernel<<<B, 64, 0, stream>>>(z, xs, xnorm, xs_h);
    dnorm_kernel<<<(N * 16 + 255) / 256, 256, 0, stream>>>(data, dnorm);
    mlp_kernel<<<B / 8, 256, 0, stream>>>(z, t_, W1, b1, W2, b2, xdot);
    sample_gemm<<<dim3(B / 64, SAMPLE / 128), 256, 0, stream>>>(data, xs, xnorm, dnorm, samp);
    thr_select<<<B, 256, 0, stream>>>(samp, thr);
    // samp is dead now; overwrite region with d_hi
    convert_data<<<(NPAD * 64 + 255) / 256, 256, 0, stream>>>(data, d_hi);
    gemm_filter<<<dim3(B / 128, NPAD / 128), 256, 0, stream>>>(
        xs_h, d_hi, xnorm, dnorm, thr, cnt, bufd, bufi);
    select_finish<<<B, 64, 0, stream>>>(bufd, bufi, cnt, xs, xnorm, dnorm, data, xdot, vel, out);
}

// Round 5
// 409.740 us; speedup vs baseline: 3.7189x; 1.5507x over previous
//
#include <hip/hip_runtime.h>
#include <math.h>

// Problem constants
#define B      2048
#define N      100000
#define NPAD   100096   // 782 * 128
#define DD     64
#define HH     256
#define KK     20
#define SAMPLE 4096
#define CAP    1536
#define SSEL   320
#define SLACK  1.5f
#define LCAP   12       // per-row per-block LDS bucket slots

#define INF_F (__builtin_inff())

typedef __bf16 bf16x8 __attribute__((ext_vector_type(8)));
typedef __bf16 bf16x4 __attribute__((ext_vector_type(4)));
typedef float  floatx4 __attribute__((ext_vector_type(4)));
union U16 { uint4 u; bf16x8 v; };

__device__ __forceinline__ float wsum64(float v) {
    #pragma unroll
    for (int o = 32; o > 0; o >>= 1) v += __shfl_xor(v, o, 64);
    return v;
}

// ---------------------------------------------------------------- prep ------
__global__ __launch_bounds__(64) void prep_kernel(const float* __restrict__ z,
                                                  float* __restrict__ xs,
                                                  float* __restrict__ xnorm,
                                                  __bf16* __restrict__ xs_h) {
    int b = blockIdx.x, d = threadIdx.x;
    float v = z[b * 66 + d];
    xs[b * 64 + d] = v;
    xs_h[b * 64 + d] = (__bf16)v;
    float s = wsum64(v * v);
    if (d == 0) xnorm[b] = s;
}

// --------------------------------------------------------------- dnorm ------
__global__ __launch_bounds__(256) void dnorm_kernel(const float* __restrict__ data,
                                                    float* __restrict__ dnorm) {
    int gt = blockIdx.x * 256 + threadIdx.x;
    int j = gt >> 4;
    int l = gt & 15;
    if (j >= N) return;
    const float4* dp = reinterpret_cast<const float4*>(data + (size_t)j * 64);
    float4 v = dp[l];
    float s = v.x * v.x + v.y * v.y + v.z * v.z + v.w * v.w;
    #pragma unroll
    for (int o = 1; o < 16; o <<= 1) s += __shfl_xor(s, o, 64);
    if (l == 0) dnorm[j] = s;
}

// ---------------------------------------------------------- convert data ----
__global__ __launch_bounds__(256) void convert_data(const float* __restrict__ data,
                                                    __bf16* __restrict__ d_hi) {
    int gt = blockIdx.x * 256 + threadIdx.x;
    int j = gt >> 4;
    int l = gt & 15;
    if (j >= NPAD) return;
    float4 v = make_float4(0.f, 0.f, 0.f, 0.f);
    if (j < N)
        v = reinterpret_cast<const float4*>(data + (size_t)j * 64)[l];
    bf16x4 o;
    o.x = (__bf16)v.x; o.y = (__bf16)v.y; o.z = (__bf16)v.z; o.w = (__bf16)v.w;
    *reinterpret_cast<bf16x4*>(d_hi + (size_t)j * 64 + l * 4) = o;
}

// ---------------------------------------------------------------- mlp -------
__global__ __launch_bounds__(256) void mlp_kernel(const float* __restrict__ z,
                                                  const float* __restrict__ tp,
                                                  const float* __restrict__ W1,
                                                  const float* __restrict__ b1,
                                                  const float* __restrict__ W2,
                                                  const float* __restrict__ b2,
                                                  float* __restrict__ xdot) {
    __shared__ float sin_[8][65];
    __shared__ float shid[8][HH];
    int tid = threadIdx.x;
    int row0 = blockIdx.x * 8;
    float tval = tp[0];
    for (int idx = tid; idx < 8 * 64; idx += 256) {
        int r = idx >> 6, d = idx & 63;
        sin_[r][d] = z[(row0 + r) * 66 + d];
    }
    if (tid < 8) sin_[tid][64] = tval;
    __syncthreads();

    int h = tid;
    float acc[8];
    #pragma unroll
    for (int r = 0; r < 8; ++r) acc[r] = b1[h];
    for (int i = 0; i < 65; ++i) {
        float wv = W1[i * HH + h];
        #pragma unroll
        for (int r = 0; r < 8; ++r) acc[r] = fmaf(sin_[r][i], wv, acc[r]);
    }
    #pragma unroll
    for (int r = 0; r < 8; ++r) shid[r][h] = fmaxf(acc[r], 0.f);
    __syncthreads();

    int d = tid & 63, rb = tid >> 6;
    for (int rr = rb; rr < 8; rr += 4) {
        float a = b2[d];
        #pragma unroll 8
        for (int hh2 = 0; hh2 < HH; ++hh2)
            a = fmaf(shid[rr][hh2], W2[hh2 * 64 + d], a);
        xdot[(size_t)(row0 + rr) * 64 + d] = a;
    }
}

// ------------------------------------------------ exact sample dist GEMM ----
__global__ __launch_bounds__(256) void sample_gemm(const float* __restrict__ data,
                                                   const float* __restrict__ xs,
                                                   const float* __restrict__ xnorm,
                                                   const float* __restrict__ dnorm,
                                                   float* __restrict__ samp) {
    __shared__ float sx[64][64];
    __shared__ float sd[64][128];
    int tid = threadIdx.x;
    int row0 = blockIdx.x * 64;
    int j0 = blockIdx.y * 128;
    #pragma unroll
    for (int p = 0; p < 4; ++p) {
        int flat = p * 256 + tid;
        int m = flat & 63, k4 = flat >> 6;
        float4 v = *reinterpret_cast<const float4*>(xs + (row0 + m) * 64 + k4 * 4);
        sx[k4 * 4 + 0][m] = v.x; sx[k4 * 4 + 1][m] = v.y;
        sx[k4 * 4 + 2][m] = v.z; sx[k4 * 4 + 3][m] = v.w;
    }
    #pragma unroll
    for (int p = 0; p < 8; ++p) {
        int flat = p * 256 + tid;
        int n = flat & 127, k4 = flat >> 7;
        float4 v = *reinterpret_cast<const float4*>(data + (size_t)(j0 + n) * 64 + k4 * 4);
        sd[k4 * 4 + 0][n] = v.x; sd[k4 * 4 + 1][n] = v.y;
        sd[k4 * 4 + 2][n] = v.z; sd[k4 * 4 + 3][n] = v.w;
    }
    __syncthreads();

    int tx = tid & 15, ty = tid >> 4;
    int m0 = ty * 4, n0 = tx * 8;
    float acc[4][8];
    #pragma unroll
    for (int r = 0; r < 4; ++r)
        #pragma unroll
        for (int c = 0; c < 8; ++c) acc[r][c] = 0.f;
    #pragma unroll 8
    for (int k = 0; k < 64; ++k) {
        float4 a  = *reinterpret_cast<const float4*>(&sx[k][m0]);
        float4 b0 = *reinterpret_cast<const float4*>(&sd[k][n0]);
        float4 b1 = *reinterpret_cast<const float4*>(&sd[k][n0 + 4]);
        float av[4] = {a.x, a.y, a.z, a.w};
        float bv[8] = {b0.x, b0.y, b0.z, b0.w, b1.x, b1.y, b1.z, b1.w};
        #pragma unroll
        for (int r = 0; r < 4; ++r)
            #pragma unroll
            for (int c = 0; c < 8; ++c)
                acc[r][c] = fmaf(av[r], bv[c], acc[r][c]);
    }
    #pragma unroll
    for (int r = 0; r < 4; ++r) {
        int row = row0 + m0 + r;
        float xn = xnorm[row];
        #pragma unroll
        for (int c = 0; c < 8; ++c) {
            int j = j0 + n0 + c;
            samp[(size_t)row * SAMPLE + j] = xn + dnorm[j] - 2.0f * acc[r][c];
        }
    }
}

// ------------------------------------------------------------ thr select ----
__global__ __launch_bounds__(256) void thr_select(const float* __restrict__ samp,
                                                  float* __restrict__ thr) {
    __shared__ float s[SAMPLE];
    __shared__ float wmin[4];
    __shared__ int   wpos[4];
    int row = blockIdx.x, tid = threadIdx.x;
    for (int i = tid; i < SAMPLE; i += 256) s[i] = samp[(size_t)row * SAMPLE + i];
    __syncthreads();
    for (int k = 0; k < KK; ++k) {
        float v = INF_F; int p = -1;
        #pragma unroll
        for (int u = 0; u < SAMPLE / 256; ++u) {
            int i = u * 256 + tid;
            float x = s[i];
            if (x < v) { v = x; p = i; }
        }
        #pragma unroll
        for (int o = 32; o > 0; o >>= 1) {
            float ov = __shfl_xor(v, o, 64);
            int op = __shfl_xor(p, o, 64);
            if (ov < v) { v = ov; p = op; }
        }
        if ((tid & 63) == 0) { wmin[tid >> 6] = v; wpos[tid >> 6] = p; }
        __syncthreads();
        if (tid == 0) {
            float bv = wmin[0]; int bp = wpos[0];
            #pragma unroll
            for (int w = 1; w < 4; ++w)
                if (wmin[w] < bv) { bv = wmin[w]; bp = wpos[w]; }
            if (bp >= 0) s[bp] = INF_F;
            if (k == KK - 1) thr[row] = bv;
        }
        __syncthreads();
    }
}

// ------------------------------------------------------ bf16 MFMA filter ----
// 128x128 tile; survivors -> per-row LDS buckets -> one global atomic per row
__global__ __launch_bounds__(256) void gemm_filter(const __bf16* __restrict__ xs_h,
                                                   const __bf16* __restrict__ d_hi,
                                                   const float* __restrict__ xnorm,
                                                   const float* __restrict__ dnorm,
                                                   const float* __restrict__ thr,
                                                   int* __restrict__ cnt,
                                                   float* __restrict__ bufd,
                                                   int* __restrict__ bufi) {
    __shared__ uint4 sA[8][128];
    __shared__ uint4 sB[8][128];
    __shared__ float sXN[128], sLIM[128], sDN[128];
    __shared__ int   lcnt[128];
    __shared__ float lbd[128][LCAP];
    __shared__ int   lbj[128][LCAP];
    int tid = threadIdx.x;
    int m0 = blockIdx.x * 128;
    int j0 = blockIdx.y * 128;

    #pragma unroll
    for (int p = 0; p < 4; ++p) {
        int flat = p * 256 + tid;
        int m = flat & 127, c = flat >> 7;
        sA[c][m] = reinterpret_cast<const uint4*>(xs_h + (size_t)(m0 + m) * 64)[c];
    }
    #pragma unroll
    for (int p = 0; p < 4; ++p) {
        int flat = p * 256 + tid;
        int n = flat & 127, c = flat >> 7;
        sB[c][n] = reinterpret_cast<const uint4*>(d_hi + (size_t)(j0 + n) * 64)[c];
    }
    if (tid < 128) {
        float xn = xnorm[m0 + tid];
        sXN[tid] = xn;
        sLIM[tid] = thr[m0 + tid] + SLACK - xn;   // pass <=> dn - 2*acc <= sLIM
        lcnt[tid] = 0;
    } else {
        int n = tid - 128;
        int j = j0 + n;
        sDN[n] = (j < N) ? dnorm[j] : 0.f;
    }
    __syncthreads();

    int wv = tid >> 6;
    int wm = wv & 1, wn = wv >> 1;
    int lane = tid & 63;
    int l16 = lane & 15, quad = lane >> 4;

    floatx4 acc[4][4];
    #pragma unroll
    for (int mt = 0; mt < 4; ++mt)
        #pragma unroll
        for (int nt = 0; nt < 4; ++nt)
            acc[mt][nt] = (floatx4){0.f, 0.f, 0.f, 0.f};

    #pragma unroll
    for (int s = 0; s < 2; ++s) {
        bf16x8 af[4], bfr[4];
        #pragma unroll
        for (int mt = 0; mt < 4; ++mt) {
            U16 u; u.u = sA[s * 4 + quad][wm * 64 + mt * 16 + l16]; af[mt] = u.v;
        }
        #pragma unroll
        for (int nt = 0; nt < 4; ++nt) {
            U16 u; u.u = sB[s * 4 + quad][wn * 64 + nt * 16 + l16]; bfr[nt] = u.v;
        }
        #pragma unroll
        for (int mt = 0; mt < 4; ++mt)
            #pragma unroll
            for (int nt = 0; nt < 4; ++nt)
                acc[mt][nt] = __builtin_amdgcn_mfma_f32_16x16x32_bf16(
                    af[mt], bfr[nt], acc[mt][nt], 0, 0, 0);
    }

    #pragma unroll
    for (int nt = 0; nt < 4; ++nt) {
        int nloc = wn * 64 + nt * 16 + l16;
        int j = j0 + nloc;
        float dn = sDN[nloc];
        bool jv = (j < N);
        #pragma unroll
        for (int mt = 0; mt < 4; ++mt) {
            floatx4 a4 = acc[mt][nt];
            #pragma unroll
            for (int rg = 0; rg < 4; ++rg) {
                int mloc = wm * 64 + mt * 16 + quad * 4 + rg;
                float t = fmaf(a4[rg], -2.0f, dn);       // dn - 2*acc
                if (jv && t <= sLIM[mloc]) {
                    int pos = atomicAdd(&lcnt[mloc], 1);
                    float sqb = t + sXN[mloc];
                    if (pos < LCAP) {
                        lbd[mloc][pos] = sqb;
                        lbj[mloc][pos] = j;
                    } else {                              // ultra-rare overflow
                        int row = m0 + mloc;
                        int gp = atomicAdd(&cnt[row], 1);
                        if (gp < CAP) {
                            bufd[(size_t)row * CAP + gp] = sqb;
                            bufi[(size_t)row * CAP + gp] = j;
                        }
                    }
                }
            }
        }
    }
    __syncthreads();
    if (tid < 128) {
        int c = lcnt[tid];
        if (c > LCAP) c = LCAP;
        if (c > 0) {
            int row = m0 + tid;
            int base = atomicAdd(&cnt[row], c);
            for (int i = 0; i < c; ++i) {
                int gp = base + i;
                if (gp < CAP) {
                    bufd[(size_t)row * CAP + gp] = lbd[tid][i];
                    bufi[(size_t)row * CAP + gp] = lbj[tid][i];
                }
            }
        }
    }
}

// --------------------------------------------------------- select + finish --
__global__ __launch_bounds__(64) void select_finish(const float* __restrict__ bufd,
                                                    const int* __restrict__ bufi,
                                                    const int* __restrict__ cnt,
                                                    const float* __restrict__ xs,
                                                    const float* __restrict__ xnorm,
                                                    const float* __restrict__ dnorm,
                                                    const float* __restrict__ data,
                                                    const float* __restrict__ xdot,
                                                    const float* __restrict__ vel,
                                                    float* __restrict__ out) {
    __shared__ float sd[CAP];
    __shared__ int   si[CAP];
    __shared__ float sx[64];
    __shared__ float se[SSEL];
    __shared__ int   sj[SSEL];
    __shared__ int   scnt;
    __shared__ float seld[KK];
    __shared__ int   seli[KK];
    __shared__ float selw[KK];
    int row = blockIdx.x, lane = threadIdx.x;
    int n = cnt[row];
    if (n > CAP) n = CAP;
    for (int i = lane; i < n; i += 64) {
        sd[i] = bufd[(size_t)row * CAP + i];
        si[i] = bufi[(size_t)row * CAP + i];
    }
    sx[lane] = xs[row * 64 + lane];
    if (lane == 0) scnt = 0;
    __syncthreads();

    float T = INF_F;
    for (int k = 0; k < KK; ++k) {
        float v = INF_F; int p = -1;
        for (int i = lane; i < n; i += 64) {
            float x = sd[i];
            if (x < v) { v = x; p = i; }
        }
        #pragma unroll
        for (int o = 32; o > 0; o >>= 1) {
            float ov = __shfl_xor(v, o, 64);
            int op = __shfl_xor(p, o, 64);
            if (ov < v) { v = ov; p = op; }
        }
        T = v;
        if (lane == 0 && p >= 0) {
            sd[p] = INF_F;
            int q = scnt++;
            sj[q] = si[p];
        }
        __syncthreads();
    }
    for (int i = lane; i < n; i += 64) {
        if (sd[i] <= T + 2.0f * SLACK) {
            int q = atomicAdd(&scnt, 1);
            if (q < SSEL) sj[q] = si[i];
        }
    }
    __syncthreads();
    int m = scnt < SSEL ? scnt : SSEL;
    for (int c = lane; c < m; c += 64) {
        int j = sj[c];
        const float4* dp = reinterpret_cast<const float4*>(data + (size_t)j * 64);
        float dot = 0.f;
        #pragma unroll
        for (int kb = 0; kb < 16; ++kb) {
            float4 q = dp[kb];
            dot = fmaf(sx[kb * 4 + 0], q.x, dot);
            dot = fmaf(sx[kb * 4 + 1], q.y, dot);
            dot = fmaf(sx[kb * 4 + 2], q.z, dot);
            dot = fmaf(sx[kb * 4 + 3], q.w, dot);
        }
        se[c] = xnorm[row] + dnorm[j] - 2.0f * dot;
    }
    __syncthreads();
    for (int k = 0; k < KK; ++k) {
        float v = INF_F; int id = 0x7fffffff; int p = -1;
        for (int i = lane; i < m; i += 64) {
            float x = se[i]; int xi = sj[i];
            if (x < v || (x == v && xi < id)) { v = x; id = xi; p = i; }
        }
        #pragma unroll
        for (int o = 32; o > 0; o >>= 1) {
            float ov = __shfl_xor(v, o, 64);
            int oid = __shfl_xor(id, o, 64);
            int op  = __shfl_xor(p, o, 64);
            if (ov < v || (ov == v && oid < id)) { v = ov; id = oid; p = op; }
        }
        if (lane == 0) {
            seld[k] = v; seli[k] = id;
            if (p >= 0) se[p] = INF_F;
        }
        __syncthreads();
    }
    float d20 = sqrtf(fmaxf(seld[KK - 1], 1e-30f));
    float h = fmaxf(d20, 1e-12f);
    float wk = 0.f;
    if (lane < KK) {
        float dd = sqrtf(fmaxf(seld[lane], 1e-30f));
        wk = expf(-(dd * dd) / (2.f * h * h));
    }
    float tot = wsum64(wk) + 1e-12f;
    if (lane < KK) selw[lane] = wk / tot;
    __syncthreads();
    float u = 0.f;
    #pragma unroll
    for (int k = 0; k < KK; ++k)
        u = fmaf(selw[k], vel[(size_t)seli[k] * 64 + lane], u);
    float xd = xdot[(size_t)row * 64 + lane];
    float du  = wsum64(u * xd);
    float nu2 = wsum64(u * u);
    float nx2 = wsum64(xd * xd);
    float l2  = wsum64((u - xd) * (u - xd));
    float nu = fmaxf(sqrtf(nu2), 1e-8f);
    float nx = fmaxf(sqrtf(nx2), 1e-8f);
    out[(size_t)row * 66 + lane] = xd;
    if (lane == 0) {
        out[(size_t)row * 66 + 64] = 1.f - du / (nu * nx);
        out[(size_t)row * 66 + 65] = l2;
    }
}

// ---------------------------------------------------------------------------
extern "C" void kernel_launch(void* const* d_in, const int* in_sizes, int n_in,
                              void* d_out, int out_size, void* d_ws, size_t ws_size,
                              hipStream_t stream) {
    const float* t_   = (const float*)d_in[0];
    const float* z    = (const float*)d_in[1];
    const float* data = (const float*)d_in[2];
    const float* vel  = (const float*)d_in[3];
    const float* W1   = (const float*)d_in[4];
    const float* b1   = (const float*)d_in[5];
    const float* W2   = (const float*)d_in[6];
    const float* b2   = (const float*)d_in[7];
    float* out = (float*)d_out;

    // workspace layout (float slots, all 16B-aligned)
    float*  xs    = (float*)d_ws;                    // 131072
    float*  xnorm = xs + 131072;                     // 2048
    float*  xdot  = xnorm + 2048;                    // 131072
    float*  thr   = xdot + 131072;                   // 2048
    int*    cnt   = (int*)(thr + 2048);              // 2048
    float*  dnorm = (float*)(cnt + 2048);            // 100096 (padded)
    __bf16* xs_h  = (__bf16*)(dnorm + 100096);       // 131072 bf16 = 65536 f
    float*  R     = (float*)(xs_h + 131072);         // overlap region
    // phase 1: samp (2048*4096 f) at R; phase 2: d_hi (NPAD*64 bf16)
    float*  samp  = R;
    __bf16* d_hi  = (__bf16*)R;
    float*  bufd  = R + 3203072;                     // 2048*1536
    int*    bufi  = (int*)(bufd + (size_t)B * CAP);  // 2048*1536

    hipMemsetAsync(cnt, 0, B * sizeof(int), stream);
    prep_kernel<<<B, 64, 0, stream>>>(z, xs, xnorm, xs_h);
    dnorm_kernel<<<(N * 16 + 255) / 256, 256, 0, stream>>>(data, dnorm);
    mlp_kernel<<<B / 8, 256, 0, stream>>>(z, t_, W1, b1, W2, b2, xdot);
    sample_gemm<<<dim3(B / 64, SAMPLE / 128), 256, 0, stream>>>(data, xs, xnorm, dnorm, samp);
    thr_select<<<B, 256, 0, stream>>>(samp, thr);
    // samp dead; overwrite region with d_hi
    convert_data<<<(NPAD * 16 + 255) / 256, 256, 0, stream>>>(data, d_hi);
    gemm_filter<<<dim3(B / 128, NPAD / 128), 256, 0, stream>>>(
        xs_h, d_hi, xnorm, dnorm, thr, cnt, bufd, bufi);
    select_finish<<<B, 64, 0, stream>>>(bufd, bufi, cnt, xs, xnorm, dnorm, data, xdot, vel, out);
    (void)ws_size;
}